// Round 5
// baseline (1197.957 us; speedup 1.0000x reference)
//
#include <hip/hip_runtime.h>
#include <math.h>

#define NNODES 100000
#define NEDGES 1600000
#define CH 64
#define CH2 128
#define NLAYERS 3
#define NBLK 98            // ceil(100000 / 1024) scan blocks
#define NPASS 8
#define NBPP 25000         // blocks per pass = N/4 nodes-per-block
#define PLANE (NNODES * 8) // floats per y-plane (3.2 MB)

// ---------------- CSR build: histogram over dst ----------------

__global__ void hist_kernel(const int* __restrict__ dst, int* __restrict__ cnt, int E) {
    int t = blockIdx.x * blockDim.x + threadIdx.x;
    if (t < E) atomicAdd(&cnt[dst[t]], 1);
}

__global__ void dinv_kernel(const int* __restrict__ cnt, float* __restrict__ dinv, int n) {
    int t = blockIdx.x * blockDim.x + threadIdx.x;
    if (t < n) dinv[t] = rsqrtf((float)cnt[t] + 1.0f);   // +1 self-loop
}

// ---- 3-pass parallel exclusive scan over cnt[100000] ----

__global__ __launch_bounds__(256) void bsum_kernel(const int* __restrict__ cnt,
                                                   int* __restrict__ bsum) {
    int t = threadIdx.x;
    int base = blockIdx.x * 1024 + t * 4;
    int s = 0;
#pragma unroll
    for (int i = 0; i < 4; ++i) { int k = base + i; if (k < NNODES) s += cnt[k]; }
    __shared__ int ls[256];
    ls[t] = s; __syncthreads();
    for (int off = 128; off > 0; off >>= 1) {
        if (t < off) ls[t] += ls[t + off];
        __syncthreads();
    }
    if (t == 0) bsum[blockIdx.x] = ls[0];
}

__global__ __launch_bounds__(128) void bscan_kernel(const int* __restrict__ bsum,
                                                    int* __restrict__ boff,
                                                    int* __restrict__ rowptr) {
    __shared__ int s[128];
    int t = threadIdx.x;
    int v = (t < NBLK) ? bsum[t] : 0;
    s[t] = v; __syncthreads();
    for (int off = 1; off < 128; off <<= 1) {
        int u = (t >= off) ? s[t - off] : 0;
        __syncthreads();
        s[t] += u;
        __syncthreads();
    }
    if (t < NBLK) boff[t] = s[t] - v;   // exclusive
    if (t == 0) rowptr[NNODES] = NEDGES;
}

__global__ __launch_bounds__(256) void scanb_kernel(const int* __restrict__ cnt,
                                                    const int* __restrict__ boff,
                                                    int* __restrict__ rowptr,
                                                    int* __restrict__ cursor) {
    int t = threadIdx.x;
    int base = blockIdx.x * 1024 + t * 4;
    int v[4]; int tsum = 0;
#pragma unroll
    for (int i = 0; i < 4; ++i) { int k = base + i; v[i] = (k < NNODES) ? cnt[k] : 0; tsum += v[i]; }
    __shared__ int ls[256];
    ls[t] = tsum; __syncthreads();
    for (int off = 1; off < 256; off <<= 1) {
        int u = (t >= off) ? ls[t - off] : 0;
        __syncthreads();
        ls[t] += u;
        __syncthreads();
    }
    int run = boff[blockIdx.x] + ls[t] - tsum;
#pragma unroll
    for (int i = 0; i < 4; ++i) {
        int k = base + i;
        if (k < NNODES) { rowptr[k] = run; cursor[k] = run; run += v[i]; }
    }
}

// scatter edge srcs into CSR (dst-grouped) order; 4B per edge
__global__ void fill_kernel(const int* __restrict__ src, const int* __restrict__ dst,
                            int* __restrict__ cursor, int* __restrict__ esrc, int E) {
    int t = blockIdx.x * blockDim.x + threadIdx.x;
    if (t >= E) return;
    int d = dst[t];
    int pos = atomicAdd(&cursor[d], 1);
    esrc[pos] = src[t];
}

// ---------------- y = dinv * x in plane-planar layout ----------------
// y[p*PLANE + node*8 + c8] = dinv[node] * x[node*64 + p*8 + c8]; coalesced writes.

__global__ __launch_bounds__(256) void y0_kernel(const float* __restrict__ x,
                                                 const float* __restrict__ dinv,
                                                 float* __restrict__ y) {
    int t = blockIdx.x * 256 + threadIdx.x;
    if (t >= NNODES * CH) return;
    int p = t / PLANE;
    int r = t - p * PLANE;
    int node = r >> 3;
    int c8 = r & 7;
    y[t] = dinv[node] * x[(size_t)node * CH + p * 8 + c8];
}

// ---------------- 8-pass aggregation: z[d] = dinv[d]*(sum y[s] + y[d]) ----------------
// pass p = blockIdx/NBPP touches only y-plane p (3.2 MB -> per-XCD L2 resident).
// wave per node: 8 edge-groups x 8 channels; esrc loaded coalesced, src broadcast via shfl.

__global__ __launch_bounds__(256) void aggp_kernel(const int* __restrict__ rowptr,
                                                   const int* __restrict__ esrc,
                                                   const float* __restrict__ y,
                                                   const float* __restrict__ dinv,
                                                   float* __restrict__ z) {
    int pass = blockIdx.x / NBPP;
    int nb   = blockIdx.x - pass * NBPP;
    int w    = nb * 4 + (threadIdx.x >> 6);      // node id (N/4 = NBPP exact)
    int lane = threadIdx.x & 63;
    int g  = lane >> 3;                          // edge group 0..7
    int c8 = lane & 7;                           // channel within chunk

    const float* yp = y + (size_t)pass * PLANE;
    int start = rowptr[w];
    int end   = rowptr[w + 1];
    float acc = 0.0f;

    for (int base = start; base < end; base += 64) {
        int m = end - base; if (m > 64) m = 64;
        int e = 0;
        if (lane < m) e = __builtin_nontemporal_load(&esrc[base + lane]);  // coalesced, streamed
#pragma unroll 4
        for (int j = 0; j < m; j += 8) {
            int src = __shfl(e, j + g, 64);                  // broadcast edge src to group
            if (j + g < m) acc += yp[(size_t)src * 8 + c8];  // 32B contiguous per group
        }
    }

    // sum the 8 edge-group partials (lanes with equal c8)
    acc += __shfl_xor(acc, 8, 64);
    acc += __shfl_xor(acc, 16, 64);
    acc += __shfl_xor(acc, 32, 64);

    if (lane < 8) {
        float self = yp[(size_t)w * 8 + lane];
        float v = dinv[w] * (acc + self);
        __builtin_nontemporal_store(v, &z[(size_t)w * CH + pass * 8 + lane]);
    }
}

// ---------------- fused GEMM + bias + GLU + residual (+ y for next layer) ----------------
// x_next = (z@W)[:,:64]+b_a * sigmoid((z@W)[:,64:]+b_g) + x_old ; y_next = dinv*x_next (planar)

__global__ __launch_bounds__(256) void gemm_glu_kernel(const float* __restrict__ z,
                                                       const float* __restrict__ W,
                                                       const float* __restrict__ b,
                                                       const float* __restrict__ xold,
                                                       const float* __restrict__ dinv,
                                                       float* __restrict__ xnew,
                                                       float* __restrict__ ynext,
                                                       int write_y) {
    __shared__ float Wl[CH * CH2];   // 32 KB
    __shared__ float Zl[16 * CH];    // 4 KB
    int t = threadIdx.x;

    const float4* W4 = (const float4*)W;
    float4* Wl4 = (float4*)Wl;
#pragma unroll
    for (int i = 0; i < 8; ++i) Wl4[t + 256 * i] = W4[t + 256 * i];

    int row0 = blockIdx.x * 16;
    ((float4*)Zl)[t] = ((const float4*)(z + (size_t)row0 * CH))[t];
    __syncthreads();

    int c  = t & 63;          // channel
    int rg = t >> 6;          // 0..3 -> rows rg*4 .. rg*4+3 (wave-uniform)
    float accA[4] = {0.f, 0.f, 0.f, 0.f};
    float accG[4] = {0.f, 0.f, 0.f, 0.f};

#pragma unroll 4
    for (int k = 0; k < CH; ++k) {
        float wa = Wl[k * CH2 + c];
        float wg = Wl[k * CH2 + 64 + c];
#pragma unroll
        for (int i = 0; i < 4; ++i) {
            float zv = Zl[(rg * 4 + i) * CH + k];   // wave-uniform broadcast
            accA[i] += zv * wa;
            accG[i] += zv * wg;
        }
    }

    float ba = b[c], bg = b[64 + c];
    int pl = c >> 3, c8 = c & 7;
#pragma unroll
    for (int i = 0; i < 4; ++i) {
        int row = row0 + rg * 4 + i;
        size_t idx = (size_t)row * CH + c;
        float a = accA[i] + ba;
        float gv = accG[i] + bg;
        float sg = 1.0f / (1.0f + expf(-gv));
        float xv = a * sg + xold[idx];
        xnew[idx] = xv;
        if (write_y)
            ynext[(size_t)pl * PLANE + (size_t)row * 8 + c8] = dinv[row] * xv;
    }
}

// ---------------- launch ----------------

extern "C" void kernel_launch(void* const* d_in, const int* in_sizes, int n_in,
                              void* d_out, int out_size, void* d_ws, size_t ws_size,
                              hipStream_t stream) {
    const float* x_in = (const float*)d_in[0];              // [N,64]
    const float* Ws   = (const float*)d_in[1];              // [3,64,128]
    const float* bs   = (const float*)d_in[2];              // [3,128]
    const int*   ei   = (const int*)d_in[3];                // [2,E]
    const int* src = ei;
    const int* dst = ei + NEDGES;

    char* wsb = (char*)d_ws;
    int*   cnt    = (int*)wsb;                                 // N ints
    float* dinv   = (float*)(wsb + 1 * 512 * 1024);            // N floats
    int*   rowptr = (int*)(wsb + 2 * 512 * 1024);              // N+1
    int*   bsum   = (int*)(wsb + 2 * 512 * 1024 + 460 * 1024); // 128+128 ints (rowptr slab tail)
    int*   boff   = bsum + 128;
    int*   cursor = (int*)(wsb + 3 * 512 * 1024);              // N
    int*   esrc   = (int*)(wsb + 2 * 1024 * 1024);             // E ints = 6.4 MB
    float* y      = (float*)(wsb + 10 * 1024 * 1024);          // N*64 = 25.6 MB (8 planes)
    float* z      = (float*)(wsb + 37 * 1024 * 1024);          // N*64 = 25.6 MB
    float* xbuf   = (float*)(wsb + 64 * 1024 * 1024);          // N*64 = 25.6 MB

    // ---- CSR build (once; reused by all layers) ----
    hipMemsetAsync(cnt, 0, NNODES * sizeof(int), stream);
    hist_kernel<<<(NEDGES + 255) / 256, 256, 0, stream>>>(dst, cnt, NEDGES);
    dinv_kernel<<<(NNODES + 255) / 256, 256, 0, stream>>>(cnt, dinv, NNODES);
    bsum_kernel<<<NBLK, 256, 0, stream>>>(cnt, bsum);
    bscan_kernel<<<1, 128, 0, stream>>>(bsum, boff, rowptr);
    scanb_kernel<<<NBLK, 256, 0, stream>>>(cnt, boff, rowptr, cursor);
    fill_kernel<<<(NEDGES + 255) / 256, 256, 0, stream>>>(src, dst, cursor, esrc, NEDGES);
    y0_kernel<<<(NNODES * CH + 255) / 256, 256, 0, stream>>>(x_in, dinv, y);

    const float* xl = x_in;
    for (int l = 0; l < NLAYERS; ++l) {
        const float* W = Ws + (size_t)l * CH * CH2;
        const float* b = bs + (size_t)l * CH2;
        float* xout = (l == NLAYERS - 1) ? (float*)d_out : xbuf;

        aggp_kernel<<<NPASS * NBPP, 256, 0, stream>>>(rowptr, esrc, y, dinv, z);
        gemm_glu_kernel<<<NNODES / 16, 256, 0, stream>>>(z, W, b, xl, dinv, xout, y,
                                                         (l < NLAYERS - 1) ? 1 : 0);

        xl = xout;   // middle layer in-place on xbuf: each element read+written by one thread
    }
}

// Round 7
// 599.245 us; speedup vs baseline: 1.9991x; 1.9991x over previous
//
#include <hip/hip_runtime.h>
#include <math.h>

#define NNODES 100000
#define NEDGES 1600000
#define CH 64
#define CH2 128
#define NLAYERS 3
#define NBLK 98            // ceil(100000 / 1024) scan blocks

// ---------------- CSR build: histogram over dst ----------------

__global__ void hist_kernel(const int* __restrict__ dst, int* __restrict__ cnt, int E) {
    int t = blockIdx.x * blockDim.x + threadIdx.x;
    if (t < E) atomicAdd(&cnt[dst[t]], 1);
}

__global__ void dinv_kernel(const int* __restrict__ cnt, float* __restrict__ dinv, int n) {
    int t = blockIdx.x * blockDim.x + threadIdx.x;
    if (t < n) dinv[t] = rsqrtf((float)cnt[t] + 1.0f);   // +1 self-loop
}

// ---- 3-pass parallel exclusive scan over cnt[100000] ----

__global__ __launch_bounds__(256) void bsum_kernel(const int* __restrict__ cnt,
                                                   int* __restrict__ bsum) {
    int t = threadIdx.x;
    int base = blockIdx.x * 1024 + t * 4;
    int s = 0;
#pragma unroll
    for (int i = 0; i < 4; ++i) { int k = base + i; if (k < NNODES) s += cnt[k]; }
    __shared__ int ls[256];
    ls[t] = s; __syncthreads();
    for (int off = 128; off > 0; off >>= 1) {
        if (t < off) ls[t] += ls[t + off];
        __syncthreads();
    }
    if (t == 0) bsum[blockIdx.x] = ls[0];
}

__global__ __launch_bounds__(128) void bscan_kernel(const int* __restrict__ bsum,
                                                    int* __restrict__ boff,
                                                    int* __restrict__ rowptr) {
    __shared__ int s[128];
    int t = threadIdx.x;
    int v = (t < NBLK) ? bsum[t] : 0;
    s[t] = v; __syncthreads();
    for (int off = 1; off < 128; off <<= 1) {
        int u = (t >= off) ? s[t - off] : 0;
        __syncthreads();
        s[t] += u;
        __syncthreads();
    }
    if (t < NBLK) boff[t] = s[t] - v;   // exclusive
    if (t == 0) rowptr[NNODES] = NEDGES;
}

__global__ __launch_bounds__(256) void scanb_kernel(const int* __restrict__ cnt,
                                                    const int* __restrict__ boff,
                                                    int* __restrict__ rowptr,
                                                    int* __restrict__ cursor) {
    int t = threadIdx.x;
    int base = blockIdx.x * 1024 + t * 4;
    int v[4]; int tsum = 0;
#pragma unroll
    for (int i = 0; i < 4; ++i) { int k = base + i; v[i] = (k < NNODES) ? cnt[k] : 0; tsum += v[i]; }
    __shared__ int ls[256];
    ls[t] = tsum; __syncthreads();
    for (int off = 1; off < 256; off <<= 1) {
        int u = (t >= off) ? ls[t - off] : 0;
        __syncthreads();
        ls[t] += u;
        __syncthreads();
    }
    int run = boff[blockIdx.x] + ls[t] - tsum;
#pragma unroll
    for (int i = 0; i < 4; ++i) {
        int k = base + i;
        if (k < NNODES) { rowptr[k] = run; cursor[k] = run; run += v[i]; }
    }
}

// scatter edge srcs into CSR (dst-grouped) order; 4B per edge
__global__ void fill_kernel(const int* __restrict__ src, const int* __restrict__ dst,
                            int* __restrict__ cursor, int* __restrict__ esrc, int E) {
    int t = blockIdx.x * blockDim.x + threadIdx.x;
    if (t >= E) return;
    int d = dst[t];
    int pos = atomicAdd(&cursor[d], 1);
    esrc[pos] = src[t];
}

// ---------------- y = dinv * x (row-major), once for layer 0 ----------------

__global__ __launch_bounds__(256) void y0_kernel(const float* __restrict__ x,
                                                 const float* __restrict__ dinv,
                                                 float* __restrict__ y) {
    int t = blockIdx.x * 256 + threadIdx.x;
    if (t >= NNODES * CH) return;
    int node = t >> 6;
    y[t] = dinv[node] * x[t];
}

// ---------------- aggregation: z[d] = dinv[d]*(sum_{s in N(d)} y[s] + y[d]) ----------------
// one wave per node. 4 edges in flight per iteration: group g (16 lanes) loads the
// full 256B row of edge j+g as float4/lane. Edge indices batched 64-wide (coalesced),
// broadcast via shfl. ALL cross-lane shuffles execute wave-uniformly (round-6 bugfix:
// the tail shfl must not sit inside a divergent branch).

__global__ __launch_bounds__(256) void agg4_kernel(const int* __restrict__ rowptr,
                                                   const int* __restrict__ esrc,
                                                   const float* __restrict__ y,
                                                   const float* __restrict__ dinv,
                                                   float* __restrict__ z) {
    int w = (blockIdx.x * 256 + threadIdx.x) >> 6;   // node id
    int lane = threadIdx.x & 63;
    if (w >= NNODES) return;
    int g = lane >> 4;        // edge subgroup 0..3
    int q = lane & 15;        // quarter-row slot: float4 at channel q*4

    int start = rowptr[w];
    int end   = rowptr[w + 1];
    float4 acc = make_float4(0.f, 0.f, 0.f, 0.f);

    for (int base = start; base < end; base += 64) {
        int m = end - base; if (m > 64) m = 64;   // wave-uniform
        int e = (lane < m) ? esrc[base + lane] : 0;   // coalesced 4B/lane
        int m4 = m & ~3;
        int j = 0;
#pragma unroll 2
        for (; j < m4; j += 4) {                  // wave-uniform trip count
            int s = __shfl(e, j + g, 64);         // all lanes participate
            float4 v = *(const float4*)(y + (size_t)s * CH + q * 4);
            acc.x += v.x; acc.y += v.y; acc.z += v.z; acc.w += v.w;
        }
        if (m4 < m) {                             // wave-uniform condition
            int s = __shfl(e, m4 + g, 64);        // all lanes execute the shuffle
            if (m4 + g < m) {                     // only the load+add is predicated
                float4 v = *(const float4*)(y + (size_t)s * CH + q * 4);
                acc.x += v.x; acc.y += v.y; acc.z += v.z; acc.w += v.w;
            }
        }
    }

    // combine the 4 group partials (lanes equal mod 16) — wave-uniform
#pragma unroll
    for (int off = 16; off < 64; off <<= 1) {
        acc.x += __shfl_xor(acc.x, off, 64);
        acc.y += __shfl_xor(acc.y, off, 64);
        acc.z += __shfl_xor(acc.z, off, 64);
        acc.w += __shfl_xor(acc.w, off, 64);
    }

    if (lane < 16) {
        float4 sv = *(const float4*)(y + (size_t)w * CH + lane * 4);   // self-loop
        float dv = dinv[w];
        float4 out;
        out.x = dv * (acc.x + sv.x);
        out.y = dv * (acc.y + sv.y);
        out.z = dv * (acc.z + sv.z);
        out.w = dv * (acc.w + sv.w);
        *(float4*)(z + (size_t)w * CH + lane * 4) = out;
    }
}

// ---------------- fused GEMM + bias + GLU + residual (+ y for next layer) ----------------
// x_next = (z@W)[:,:64]+b_a * sigmoid((z@W)[:,64:]+b_g) + x_old ; y_next = dinv*x_next

__global__ __launch_bounds__(256) void gemm_glu_kernel(const float* __restrict__ z,
                                                       const float* __restrict__ W,
                                                       const float* __restrict__ b,
                                                       const float* __restrict__ xold,
                                                       const float* __restrict__ dinv,
                                                       float* __restrict__ xnew,
                                                       float* __restrict__ ynext,
                                                       int write_y) {
    __shared__ float Wl[CH * CH2];   // 32 KB
    __shared__ float Zl[16 * CH];    // 4 KB
    int t = threadIdx.x;

    const float4* W4 = (const float4*)W;
    float4* Wl4 = (float4*)Wl;
#pragma unroll
    for (int i = 0; i < 8; ++i) Wl4[t + 256 * i] = W4[t + 256 * i];

    int row0 = blockIdx.x * 16;
    ((float4*)Zl)[t] = ((const float4*)(z + (size_t)row0 * CH))[t];
    __syncthreads();

    int c  = t & 63;          // channel
    int rg = t >> 6;          // 0..3 -> rows rg*4 .. rg*4+3 (wave-uniform)
    float accA[4] = {0.f, 0.f, 0.f, 0.f};
    float accG[4] = {0.f, 0.f, 0.f, 0.f};

#pragma unroll 4
    for (int k = 0; k < CH; ++k) {
        float wa = Wl[k * CH2 + c];
        float wg = Wl[k * CH2 + 64 + c];
#pragma unroll
        for (int i = 0; i < 4; ++i) {
            float zv = Zl[(rg * 4 + i) * CH + k];   // wave-uniform broadcast
            accA[i] += zv * wa;
            accG[i] += zv * wg;
        }
    }

    float ba = b[c], bg = b[64 + c];
#pragma unroll
    for (int i = 0; i < 4; ++i) {
        int row = row0 + rg * 4 + i;
        size_t idx = (size_t)row * CH + c;
        float a = accA[i] + ba;
        float gv = accG[i] + bg;
        float sg = 1.0f / (1.0f + expf(-gv));
        float xv = a * sg + xold[idx];
        xnew[idx] = xv;
        if (write_y)
            ynext[idx] = dinv[row] * xv;
    }
}

// ---------------- launch ----------------

extern "C" void kernel_launch(void* const* d_in, const int* in_sizes, int n_in,
                              void* d_out, int out_size, void* d_ws, size_t ws_size,
                              hipStream_t stream) {
    const float* x_in = (const float*)d_in[0];              // [N,64]
    const float* Ws   = (const float*)d_in[1];              // [3,64,128]
    const float* bs   = (const float*)d_in[2];              // [3,128]
    const int*   ei   = (const int*)d_in[3];                // [2,E]
    const int* src = ei;
    const int* dst = ei + NEDGES;

    char* wsb = (char*)d_ws;
    int*   cnt    = (int*)wsb;                                 // N ints
    float* dinv   = (float*)(wsb + 1 * 512 * 1024);            // N floats
    int*   rowptr = (int*)(wsb + 2 * 512 * 1024);              // N+1
    int*   bsum   = (int*)(wsb + 2 * 512 * 1024 + 460 * 1024); // 128+128 ints (rowptr slab tail)
    int*   boff   = bsum + 128;
    int*   cursor = (int*)(wsb + 3 * 512 * 1024);              // N
    int*   esrc   = (int*)(wsb + 2 * 1024 * 1024);             // E ints = 6.4 MB
    float* y      = (float*)(wsb + 10 * 1024 * 1024);          // N*64 = 25.6 MB
    float* z      = (float*)(wsb + 37 * 1024 * 1024);          // N*64 = 25.6 MB
    float* xbuf   = (float*)(wsb + 64 * 1024 * 1024);          // N*64 = 25.6 MB

    // ---- CSR build (once; reused by all layers) ----
    hipMemsetAsync(cnt, 0, NNODES * sizeof(int), stream);
    hist_kernel<<<(NEDGES + 255) / 256, 256, 0, stream>>>(dst, cnt, NEDGES);
    dinv_kernel<<<(NNODES + 255) / 256, 256, 0, stream>>>(cnt, dinv, NNODES);
    bsum_kernel<<<NBLK, 256, 0, stream>>>(cnt, bsum);
    bscan_kernel<<<1, 128, 0, stream>>>(bsum, boff, rowptr);
    scanb_kernel<<<NBLK, 256, 0, stream>>>(cnt, boff, rowptr, cursor);
    fill_kernel<<<(NEDGES + 255) / 256, 256, 0, stream>>>(src, dst, cursor, esrc, NEDGES);
    y0_kernel<<<(NNODES * CH + 255) / 256, 256, 0, stream>>>(x_in, dinv, y);

    const float* xl = x_in;
    for (int l = 0; l < NLAYERS; ++l) {
        const float* W = Ws + (size_t)l * CH * CH2;
        const float* b = bs + (size_t)l * CH2;
        float* xout = (l == NLAYERS - 1) ? (float*)d_out : xbuf;

        agg4_kernel<<<(NNODES * 64 + 255) / 256, 256, 0, stream>>>(rowptr, esrc, y, dinv, z);
        gemm_glu_kernel<<<NNODES / 16, 256, 0, stream>>>(z, W, b, xl, dinv, xout, y,
                                                         (l < NLAYERS - 1) ? 1 : 0);

        xl = xout;   // middle layer in-place on xbuf: each element read+written by one thread
    }
}

// Round 9
// 555.143 us; speedup vs baseline: 2.1579x; 1.0794x over previous
//
#include <hip/hip_runtime.h>
#include <math.h>

#define NNODES 100000
#define NEDGES 1600000
#define CH 64
#define CH2 128
#define NLAYERS 3
#define NBLK 98            // ceil(100000 / 1024) scan blocks

typedef unsigned int uint;
typedef unsigned short ushort;

// round-to-nearest-even f32 -> bf16 (finite inputs)
__device__ __forceinline__ ushort f2bf(float f) {
    uint u = __float_as_uint(f);
    u = (u + 0x7fffu + ((u >> 16) & 1u)) >> 16;
    return (ushort)u;
}
__device__ __forceinline__ float bflo(uint p) { return __uint_as_float(p << 16); }
__device__ __forceinline__ float bfhi(uint p) { return __uint_as_float(p & 0xffff0000u); }

// ---------------- CSR build: histogram over dst ----------------

__global__ void hist_kernel(const int* __restrict__ dst, int* __restrict__ cnt, int E) {
    int t = blockIdx.x * blockDim.x + threadIdx.x;
    if (t < E) atomicAdd(&cnt[dst[t]], 1);
}

__global__ void dinv_kernel(const int* __restrict__ cnt, float* __restrict__ dinv, int n) {
    int t = blockIdx.x * blockDim.x + threadIdx.x;
    if (t < n) dinv[t] = rsqrtf((float)cnt[t] + 1.0f);   // +1 self-loop
}

// ---- 3-pass parallel exclusive scan over cnt[100000] ----

__global__ __launch_bounds__(256) void bsum_kernel(const int* __restrict__ cnt,
                                                   int* __restrict__ bsum) {
    int t = threadIdx.x;
    int base = blockIdx.x * 1024 + t * 4;
    int s = 0;
#pragma unroll
    for (int i = 0; i < 4; ++i) { int k = base + i; if (k < NNODES) s += cnt[k]; }
    __shared__ int ls[256];
    ls[t] = s; __syncthreads();
    for (int off = 128; off > 0; off >>= 1) {
        if (t < off) ls[t] += ls[t + off];
        __syncthreads();
    }
    if (t == 0) bsum[blockIdx.x] = ls[0];
}

__global__ __launch_bounds__(128) void bscan_kernel(const int* __restrict__ bsum,
                                                    int* __restrict__ boff,
                                                    int* __restrict__ rowptr) {
    __shared__ int s[128];
    int t = threadIdx.x;
    int v = (t < NBLK) ? bsum[t] : 0;
    s[t] = v; __syncthreads();
    for (int off = 1; off < 128; off <<= 1) {
        int u = (t >= off) ? s[t - off] : 0;
        __syncthreads();
        s[t] += u;
        __syncthreads();
    }
    if (t < NBLK) boff[t] = s[t] - v;   // exclusive
    if (t == 0) rowptr[NNODES] = NEDGES;
}

__global__ __launch_bounds__(256) void scanb_kernel(const int* __restrict__ cnt,
                                                    const int* __restrict__ boff,
                                                    int* __restrict__ rowptr,
                                                    int* __restrict__ cursor) {
    int t = threadIdx.x;
    int base = blockIdx.x * 1024 + t * 4;
    int v[4]; int tsum = 0;
#pragma unroll
    for (int i = 0; i < 4; ++i) { int k = base + i; v[i] = (k < NNODES) ? cnt[k] : 0; tsum += v[i]; }
    __shared__ int ls[256];
    ls[t] = tsum; __syncthreads();
    for (int off = 1; off < 256; off <<= 1) {
        int u = (t >= off) ? ls[t - off] : 0;
        __syncthreads();
        ls[t] += u;
        __syncthreads();
    }
    int run = boff[blockIdx.x] + ls[t] - tsum;
#pragma unroll
    for (int i = 0; i < 4; ++i) {
        int k = base + i;
        if (k < NNODES) { rowptr[k] = run; cursor[k] = run; run += v[i]; }
    }
}

// scatter edge srcs into CSR (dst-grouped) order; 4B per edge
__global__ void fill_kernel(const int* __restrict__ src, const int* __restrict__ dst,
                            int* __restrict__ cursor, int* __restrict__ esrc, int E) {
    int t = blockIdx.x * blockDim.x + threadIdx.x;
    if (t >= E) return;
    int d = dst[t];
    int pos = atomicAdd(&cursor[d], 1);
    esrc[pos] = src[t];
}

// ---------------- y = bf16(dinv * x) (row-major), once for layer 0 ----------------

__global__ __launch_bounds__(256) void y0_kernel(const float* __restrict__ x,
                                                 const float* __restrict__ dinv,
                                                 ushort* __restrict__ y) {
    int t = blockIdx.x * 256 + threadIdx.x;
    if (t >= NNODES * CH) return;
    int node = t >> 6;
    y[t] = f2bf(dinv[node] * x[t]);
}

// ---------------- aggregation: z[d] = dinv[d]*(sum_{s in N(d)} y[s] + y[d]) ----------------
// y is bf16: a node row is 128B = 2 cache lines (vs 4 in f32). One wave per node,
// 4 edges in flight: group g (16 lanes) loads edge j+g's row as ushort4 (8B)/lane.
// f32 accumulation. All shuffles wave-uniform.

__global__ __launch_bounds__(256) void agg4_kernel(const int* __restrict__ rowptr,
                                                   const int* __restrict__ esrc,
                                                   const ushort* __restrict__ y,
                                                   const float* __restrict__ dinv,
                                                   float* __restrict__ z) {
    int w = (blockIdx.x * 256 + threadIdx.x) >> 6;   // node id
    int lane = threadIdx.x & 63;
    if (w >= NNODES) return;
    int g = lane >> 4;        // edge subgroup 0..3
    int q = lane & 15;        // slot: 4 bf16 channels at q*4

    int start = rowptr[w];
    int end   = rowptr[w + 1];
    float4 acc = make_float4(0.f, 0.f, 0.f, 0.f);

    for (int base = start; base < end; base += 64) {
        int m = end - base; if (m > 64) m = 64;       // wave-uniform
        int e = (lane < m) ? esrc[base + lane] : 0;   // coalesced 4B/lane
        int m4 = m & ~3;
        int j = 0;
#pragma unroll 2
        for (; j < m4; j += 4) {                      // wave-uniform trip count
            int s = __shfl(e, j + g, 64);
            uint2 v = *(const uint2*)(y + (size_t)s * CH + q * 4);
            acc.x += bflo(v.x); acc.y += bfhi(v.x);
            acc.z += bflo(v.y); acc.w += bfhi(v.y);
        }
        if (m4 < m) {                                 // wave-uniform condition
            int s = __shfl(e, m4 + g, 64);            // all lanes execute the shuffle
            if (m4 + g < m) {                         // only load+add predicated
                uint2 v = *(const uint2*)(y + (size_t)s * CH + q * 4);
                acc.x += bflo(v.x); acc.y += bfhi(v.x);
                acc.z += bflo(v.y); acc.w += bfhi(v.y);
            }
        }
    }

    // combine the 4 group partials (lanes equal mod 16) — wave-uniform
#pragma unroll
    for (int off = 16; off < 64; off <<= 1) {
        acc.x += __shfl_xor(acc.x, off, 64);
        acc.y += __shfl_xor(acc.y, off, 64);
        acc.z += __shfl_xor(acc.z, off, 64);
        acc.w += __shfl_xor(acc.w, off, 64);
    }

    if (lane < 16) {
        uint2 sv = *(const uint2*)(y + (size_t)w * CH + lane * 4);   // self-loop
        float dv = dinv[w];
        float4 out;
        out.x = dv * (acc.x + bflo(sv.x));
        out.y = dv * (acc.y + bfhi(sv.x));
        out.z = dv * (acc.z + bflo(sv.y));
        out.w = dv * (acc.w + bfhi(sv.y));
        *(float4*)(z + (size_t)w * CH + lane * 4) = out;
    }
}

// ---------------- fused GEMM + bias + GLU + residual (+ bf16 y for next layer) ----------------
// x_next = (z@W)[:,:64]+b_a * sigmoid((z@W)[:,64:]+b_g) + x_old ; y_next = bf16(dinv*x_next)

__global__ __launch_bounds__(256) void gemm_glu_kernel(const float* __restrict__ z,
                                                       const float* __restrict__ W,
                                                       const float* __restrict__ b,
                                                       const float* __restrict__ xold,
                                                       const float* __restrict__ dinv,
                                                       float* __restrict__ xnew,
                                                       ushort* __restrict__ ynext,
                                                       int write_y) {
    __shared__ float Wl[CH * CH2];   // 32 KB
    __shared__ float Zl[16 * CH];    // 4 KB
    int t = threadIdx.x;

    const float4* W4 = (const float4*)W;
    float4* Wl4 = (float4*)Wl;
#pragma unroll
    for (int i = 0; i < 8; ++i) Wl4[t + 256 * i] = W4[t + 256 * i];

    int row0 = blockIdx.x * 16;
    ((float4*)Zl)[t] = ((const float4*)(z + (size_t)row0 * CH))[t];
    __syncthreads();

    int c  = t & 63;          // channel
    int rg = t >> 6;          // 0..3 -> rows rg*4 .. rg*4+3 (wave-uniform)
    float accA[4] = {0.f, 0.f, 0.f, 0.f};
    float accG[4] = {0.f, 0.f, 0.f, 0.f};

#pragma unroll 4
    for (int k = 0; k < CH; ++k) {
        float wa = Wl[k * CH2 + c];
        float wg = Wl[k * CH2 + 64 + c];
#pragma unroll
        for (int i = 0; i < 4; ++i) {
            float zv = Zl[(rg * 4 + i) * CH + k];   // wave-uniform broadcast
            accA[i] += zv * wa;
            accG[i] += zv * wg;
        }
    }

    float ba = b[c], bg = b[64 + c];
#pragma unroll
    for (int i = 0; i < 4; ++i) {
        int row = row0 + rg * 4 + i;
        size_t idx = (size_t)row * CH + c;
        float a = accA[i] + ba;
        float gv = accG[i] + bg;
        float sg = 1.0f / (1.0f + expf(-gv));
        float xv = a * sg + xold[idx];
        xnew[idx] = xv;
        if (write_y)
            ynext[idx] = f2bf(dinv[row] * xv);
    }
}

// ---------------- launch ----------------

extern "C" void kernel_launch(void* const* d_in, const int* in_sizes, int n_in,
                              void* d_out, int out_size, void* d_ws, size_t ws_size,
                              hipStream_t stream) {
    const float* x_in = (const float*)d_in[0];              // [N,64]
    const float* Ws   = (const float*)d_in[1];              // [3,64,128]
    const float* bs   = (const float*)d_in[2];              // [3,128]
    const int*   ei   = (const int*)d_in[3];                // [2,E]
    const int* src = ei;
    const int* dst = ei + NEDGES;

    char* wsb = (char*)d_ws;
    int*    cnt    = (int*)wsb;                                 // N ints
    float*  dinv   = (float*)(wsb + 1 * 512 * 1024);            // N floats
    int*    rowptr = (int*)(wsb + 2 * 512 * 1024);              // N+1
    int*    bsum   = (int*)(wsb + 2 * 512 * 1024 + 460 * 1024); // 128+128 ints (rowptr slab tail)
    int*    boff   = bsum + 128;
    int*    cursor = (int*)(wsb + 3 * 512 * 1024);              // N
    int*    esrc   = (int*)(wsb + 2 * 1024 * 1024);             // E ints = 6.4 MB
    ushort* y      = (ushort*)(wsb + 10 * 1024 * 1024);         // N*64 bf16 = 12.8 MB
    float*  z      = (float*)(wsb + 24 * 1024 * 1024);          // N*64 f32 = 25.6 MB
    float*  xbuf   = (float*)(wsb + 52 * 1024 * 1024);          // N*64 f32 = 25.6 MB

    // ---- CSR build (once; reused by all layers) ----
    hipMemsetAsync(cnt, 0, NNODES * sizeof(int), stream);
    hist_kernel<<<(NEDGES + 255) / 256, 256, 0, stream>>>(dst, cnt, NEDGES);
    dinv_kernel<<<(NNODES + 255) / 256, 256, 0, stream>>>(cnt, dinv, NNODES);
    bsum_kernel<<<NBLK, 256, 0, stream>>>(cnt, bsum);
    bscan_kernel<<<1, 128, 0, stream>>>(bsum, boff, rowptr);
    scanb_kernel<<<NBLK, 256, 0, stream>>>(cnt, boff, rowptr, cursor);
    fill_kernel<<<(NEDGES + 255) / 256, 256, 0, stream>>>(src, dst, cursor, esrc, NEDGES);
    y0_kernel<<<(NNODES * CH + 255) / 256, 256, 0, stream>>>(x_in, dinv, y);

    const float* xl = x_in;
    for (int l = 0; l < NLAYERS; ++l) {
        const float* W = Ws + (size_t)l * CH * CH2;
        const float* b = bs + (size_t)l * CH2;
        float* xout = (l == NLAYERS - 1) ? (float*)d_out : xbuf;

        agg4_kernel<<<(NNODES * 64 + 255) / 256, 256, 0, stream>>>(rowptr, esrc, y, dinv, z);
        gemm_glu_kernel<<<NNODES / 16, 256, 0, stream>>>(z, W, b, xl, dinv, xout, y,
                                                         (l < NLAYERS - 1) ? 1 : 0);

        xl = xout;   // middle layer in-place on xbuf: each element read+written by one thread
    }
}

// Round 10
// 539.994 us; speedup vs baseline: 2.2185x; 1.0281x over previous
//
#include <hip/hip_runtime.h>
#include <math.h>

#define NNODES 100000
#define NEDGES 1600000
#define CH 64
#define CH2 128
#define NLAYERS 3
#define NBLK 98            // ceil(100000 / 1024) scan blocks
#define NB 4096            // dst buckets for the CSR build
#define NPB 25             // nodes per bucket (4096*25 = 102400 >= N)

typedef unsigned int uint;
typedef unsigned short ushort;

// round-to-nearest-even f32 -> bf16 (finite inputs)
__device__ __forceinline__ ushort f2bf(float f) {
    uint u = __float_as_uint(f);
    u = (u + 0x7fffu + ((u >> 16) & 1u)) >> 16;
    return (ushort)u;
}
__device__ __forceinline__ float bflo(uint p) { return __uint_as_float(p << 16); }
__device__ __forceinline__ float bfhi(uint p) { return __uint_as_float(p & 0xffff0000u); }

// ---------------- degree histogram over dst ----------------

__global__ void hist_kernel(const int* __restrict__ dst, int* __restrict__ cnt, int E) {
    int t = blockIdx.x * blockDim.x + threadIdx.x;
    if (t < E) atomicAdd(&cnt[dst[t]], 1);
}

__global__ void dinv_kernel(const int* __restrict__ cnt, float* __restrict__ dinv, int n) {
    int t = blockIdx.x * blockDim.x + threadIdx.x;
    if (t < n) dinv[t] = rsqrtf((float)cnt[t] + 1.0f);   // +1 self-loop
}

// ---- 3-pass parallel exclusive scan over cnt[100000] -> rowptr ----

__global__ __launch_bounds__(256) void bsum_kernel(const int* __restrict__ cnt,
                                                   int* __restrict__ bsum) {
    int t = threadIdx.x;
    int base = blockIdx.x * 1024 + t * 4;
    int s = 0;
#pragma unroll
    for (int i = 0; i < 4; ++i) { int k = base + i; if (k < NNODES) s += cnt[k]; }
    __shared__ int ls[256];
    ls[t] = s; __syncthreads();
    for (int off = 128; off > 0; off >>= 1) {
        if (t < off) ls[t] += ls[t + off];
        __syncthreads();
    }
    if (t == 0) bsum[blockIdx.x] = ls[0];
}

__global__ __launch_bounds__(128) void bscan_kernel(const int* __restrict__ bsum,
                                                    int* __restrict__ boff,
                                                    int* __restrict__ rowptr) {
    __shared__ int s[128];
    int t = threadIdx.x;
    int v = (t < NBLK) ? bsum[t] : 0;
    s[t] = v; __syncthreads();
    for (int off = 1; off < 128; off <<= 1) {
        int u = (t >= off) ? s[t - off] : 0;
        __syncthreads();
        s[t] += u;
        __syncthreads();
    }
    if (t < NBLK) boff[t] = s[t] - v;   // exclusive
    if (t == 0) rowptr[NNODES] = NEDGES;
}

__global__ __launch_bounds__(256) void scanb_kernel(const int* __restrict__ cnt,
                                                    const int* __restrict__ boff,
                                                    int* __restrict__ rowptr) {
    int t = threadIdx.x;
    int base = blockIdx.x * 1024 + t * 4;
    int v[4]; int tsum = 0;
#pragma unroll
    for (int i = 0; i < 4; ++i) { int k = base + i; v[i] = (k < NNODES) ? cnt[k] : 0; tsum += v[i]; }
    __shared__ int ls[256];
    ls[t] = tsum; __syncthreads();
    for (int off = 1; off < 256; off <<= 1) {
        int u = (t >= off) ? ls[t - off] : 0;
        __syncthreads();
        ls[t] += u;
        __syncthreads();
    }
    int run = boff[blockIdx.x] + ls[t] - tsum;
#pragma unroll
    for (int i = 0; i < 4; ++i) {
        int k = base + i;
        if (k < NNODES) { rowptr[k] = run; run += v[i]; }
    }
}

// ---------------- 2-level CSR fill (replaces single-level scatter) ----------------
// Level 1: scatter (src,dst) into 4096 dst-buckets; bucket region = rowptr[b*NPB..].
// Consecutive cursor claims -> near-sequential writes within a ~3KB region.

__global__ void binit_kernel(const int* __restrict__ rowptr, int* __restrict__ bcur) {
    int b = blockIdx.x * 256 + threadIdx.x;
    if (b < NB) {
        int n0 = b * NPB; if (n0 > NNODES) n0 = NNODES;
        bcur[b] = rowptr[n0];
    }
}

__global__ void bfill_kernel(const int* __restrict__ src, const int* __restrict__ dst,
                             int* __restrict__ bcur, int2* __restrict__ epair, int E) {
    int t = blockIdx.x * blockDim.x + threadIdx.x;
    if (t >= E) return;
    int s = src[t];
    int d = dst[t];
    int pos = atomicAdd(&bcur[d / NPB], 1);
    epair[pos] = make_int2(s, d);
}

// Level 2: one block per bucket; place srcs at exact rowptr positions via LDS cursors.
// All writes land inside the bucket's own segment (~1.6KB) -> single-XCD, L1-resident.

__global__ __launch_bounds__(256) void bsort_kernel(const int* __restrict__ rowptr,
                                                    const int2* __restrict__ epair,
                                                    int* __restrict__ esrc) {
    __shared__ int cur[NPB];
    int b0 = blockIdx.x;
    int n0 = b0 * NPB;
    if (n0 >= NNODES) return;
    int n1 = n0 + NPB; if (n1 > NNODES) n1 = NNODES;
    int t = threadIdx.x;
    if (t < n1 - n0) cur[t] = rowptr[n0 + t];
    __syncthreads();
    int seg_start = rowptr[n0];
    int seg_end   = rowptr[n1];
    for (int i = seg_start + t; i < seg_end; i += 256) {
        int2 p = epair[i];
        int pos = atomicAdd(&cur[p.y - n0], 1);
        esrc[pos] = p.x;
    }
}

// ---------------- y = bf16(dinv * x) (row-major), once for layer 0 ----------------

__global__ __launch_bounds__(256) void y0_kernel(const float* __restrict__ x,
                                                 const float* __restrict__ dinv,
                                                 ushort* __restrict__ y) {
    int t = blockIdx.x * 256 + threadIdx.x;
    if (t >= NNODES * CH) return;
    int node = t >> 6;
    y[t] = f2bf(dinv[node] * x[t]);
}

// ---------------- aggregation: z[d] = dinv[d]*(sum_{s in N(d)} y[s] + y[d]) ----------------
// bf16 y, 8 edges in flight per iteration: group g (8 lanes) loads edge j+g's 128B row
// as uint4 (16B = 8 bf16)/lane. f32 accumulation. All shuffles wave-uniform.

__global__ __launch_bounds__(256) void agg8_kernel(const int* __restrict__ rowptr,
                                                   const int* __restrict__ esrc,
                                                   const ushort* __restrict__ y,
                                                   const float* __restrict__ dinv,
                                                   float* __restrict__ z) {
    int w = (blockIdx.x * 256 + threadIdx.x) >> 6;   // node id
    int lane = threadIdx.x & 63;
    if (w >= NNODES) return;
    int g = lane >> 3;        // edge subgroup 0..7
    int q = lane & 7;         // slot: 8 bf16 channels at q*8

    int start = rowptr[w];
    int end   = rowptr[w + 1];
    float acc[8];
#pragma unroll
    for (int i = 0; i < 8; ++i) acc[i] = 0.0f;

    for (int base = start; base < end; base += 64) {
        int m = end - base; if (m > 64) m = 64;       // wave-uniform
        int e = (lane < m) ? esrc[base + lane] : 0;   // coalesced 4B/lane
        int m8 = m & ~7;
        int j = 0;
#pragma unroll 2
        for (; j < m8; j += 8) {                      // wave-uniform trip count
            int s = __shfl(e, j + g, 64);
            uint4 v = *(const uint4*)(y + (size_t)s * CH + q * 8);
            acc[0] += bflo(v.x); acc[1] += bfhi(v.x);
            acc[2] += bflo(v.y); acc[3] += bfhi(v.y);
            acc[4] += bflo(v.z); acc[5] += bfhi(v.z);
            acc[6] += bflo(v.w); acc[7] += bfhi(v.w);
        }
        if (m8 < m) {                                 // wave-uniform condition
            int s = __shfl(e, m8 + g, 64);            // all lanes execute the shuffle
            if (m8 + g < m) {                         // only load+add predicated
                uint4 v = *(const uint4*)(y + (size_t)s * CH + q * 8);
                acc[0] += bflo(v.x); acc[1] += bfhi(v.x);
                acc[2] += bflo(v.y); acc[3] += bfhi(v.y);
                acc[4] += bflo(v.z); acc[5] += bfhi(v.z);
                acc[6] += bflo(v.w); acc[7] += bfhi(v.w);
            }
        }
    }

    // combine the 8 group partials (lanes equal mod 8) — wave-uniform
#pragma unroll
    for (int off = 8; off < 64; off <<= 1) {
#pragma unroll
        for (int i = 0; i < 8; ++i)
            acc[i] += __shfl_xor(acc[i], off, 64);
    }

    if (lane < 8) {
        uint4 sv = *(const uint4*)(y + (size_t)w * CH + lane * 8);   // self-loop
        float dv = dinv[w];
        float4 o0, o1;
        o0.x = dv * (acc[0] + bflo(sv.x));
        o0.y = dv * (acc[1] + bfhi(sv.x));
        o0.z = dv * (acc[2] + bflo(sv.y));
        o0.w = dv * (acc[3] + bfhi(sv.y));
        o1.x = dv * (acc[4] + bflo(sv.z));
        o1.y = dv * (acc[5] + bfhi(sv.z));
        o1.z = dv * (acc[6] + bflo(sv.w));
        o1.w = dv * (acc[7] + bfhi(sv.w));
        *(float4*)(z + (size_t)w * CH + lane * 8)     = o0;
        *(float4*)(z + (size_t)w * CH + lane * 8 + 4) = o1;
    }
}

// ---------------- fused GEMM + bias + GLU + residual (+ bf16 y for next layer) ----------------

__global__ __launch_bounds__(256) void gemm_glu_kernel(const float* __restrict__ z,
                                                       const float* __restrict__ W,
                                                       const float* __restrict__ b,
                                                       const float* __restrict__ xold,
                                                       const float* __restrict__ dinv,
                                                       float* __restrict__ xnew,
                                                       ushort* __restrict__ ynext,
                                                       int write_y) {
    __shared__ float Wl[CH * CH2];   // 32 KB
    __shared__ float Zl[16 * CH];    // 4 KB
    int t = threadIdx.x;

    const float4* W4 = (const float4*)W;
    float4* Wl4 = (float4*)Wl;
#pragma unroll
    for (int i = 0; i < 8; ++i) Wl4[t + 256 * i] = W4[t + 256 * i];

    int row0 = blockIdx.x * 16;
    ((float4*)Zl)[t] = ((const float4*)(z + (size_t)row0 * CH))[t];
    __syncthreads();

    int c  = t & 63;          // channel
    int rg = t >> 6;          // 0..3 -> rows rg*4 .. rg*4+3 (wave-uniform)
    float accA[4] = {0.f, 0.f, 0.f, 0.f};
    float accG[4] = {0.f, 0.f, 0.f, 0.f};

#pragma unroll 4
    for (int k = 0; k < CH; ++k) {
        float wa = Wl[k * CH2 + c];
        float wg = Wl[k * CH2 + 64 + c];
#pragma unroll
        for (int i = 0; i < 4; ++i) {
            float zv = Zl[(rg * 4 + i) * CH + k];   // wave-uniform broadcast
            accA[i] += zv * wa;
            accG[i] += zv * wg;
        }
    }

    float ba = b[c], bg = b[64 + c];
#pragma unroll
    for (int i = 0; i < 4; ++i) {
        int row = row0 + rg * 4 + i;
        size_t idx = (size_t)row * CH + c;
        float a = accA[i] + ba;
        float gv = accG[i] + bg;
        float sg = 1.0f / (1.0f + expf(-gv));
        float xv = a * sg + xold[idx];
        xnew[idx] = xv;
        if (write_y)
            ynext[idx] = f2bf(dinv[row] * xv);
    }
}

// ---------------- launch ----------------

extern "C" void kernel_launch(void* const* d_in, const int* in_sizes, int n_in,
                              void* d_out, int out_size, void* d_ws, size_t ws_size,
                              hipStream_t stream) {
    const float* x_in = (const float*)d_in[0];              // [N,64]
    const float* Ws   = (const float*)d_in[1];              // [3,64,128]
    const float* bs   = (const float*)d_in[2];              // [3,128]
    const int*   ei   = (const int*)d_in[3];                // [2,E]
    const int* src = ei;
    const int* dst = ei + NEDGES;

    char* wsb = (char*)d_ws;
    int*    cnt    = (int*)wsb;                               // 400KB
    float*  dinv   = (float*)(wsb + 512 * 1024);              // 400KB
    int*    rowptr = (int*)(wsb + 1024 * 1024);               // 400KB+4
    int*    bsum   = (int*)(wsb + 1536 * 1024);               // 98 ints
    int*    boff   = bsum + 128;
    int*    bcur   = (int*)(wsb + 1792 * 1024);               // 16KB
    int*    esrc   = (int*)(wsb + 2 * 1024 * 1024);           // E ints = 6.4 MB
    int2*   epair  = (int2*)(wsb + 9 * 1024 * 1024);          // E int2 = 12.8 MB
    ushort* y      = (ushort*)(wsb + 22 * 1024 * 1024);       // N*64 bf16 = 12.8 MB
    float*  z      = (float*)(wsb + 35 * 1024 * 1024);        // N*64 f32 = 25.6 MB
    float*  xbuf   = (float*)(wsb + 61 * 1024 * 1024);        // N*64 f32 = 25.6 MB

    // ---- CSR build (once; reused by all layers) ----
    hipMemsetAsync(cnt, 0, NNODES * sizeof(int), stream);
    hist_kernel<<<(NEDGES + 255) / 256, 256, 0, stream>>>(dst, cnt, NEDGES);
    dinv_kernel<<<(NNODES + 255) / 256, 256, 0, stream>>>(cnt, dinv, NNODES);
    bsum_kernel<<<NBLK, 256, 0, stream>>>(cnt, bsum);
    bscan_kernel<<<1, 128, 0, stream>>>(bsum, boff, rowptr);
    scanb_kernel<<<NBLK, 256, 0, stream>>>(cnt, boff, rowptr);
    binit_kernel<<<(NB + 255) / 256, 256, 0, stream>>>(rowptr, bcur);
    bfill_kernel<<<(NEDGES + 255) / 256, 256, 0, stream>>>(src, dst, bcur, epair, NEDGES);
    bsort_kernel<<<NB, 256, 0, stream>>>(rowptr, epair, esrc);
    y0_kernel<<<(NNODES * CH + 255) / 256, 256, 0, stream>>>(x_in, dinv, y);

    const float* xl = x_in;
    for (int l = 0; l < NLAYERS; ++l) {
        const float* W = Ws + (size_t)l * CH * CH2;
        const float* b = bs + (size_t)l * CH2;
        float* xout = (l == NLAYERS - 1) ? (float*)d_out : xbuf;

        agg8_kernel<<<(NNODES * 64 + 255) / 256, 256, 0, stream>>>(rowptr, esrc, y, dinv, z);
        gemm_glu_kernel<<<NNODES / 16, 256, 0, stream>>>(z, W, b, xl, dinv, xout, y,
                                                         (l < NLAYERS - 1) ? 1 : 0);

        xl = xout;   // middle layer in-place on xbuf: each element read+written by one thread
    }
}

// Round 11
// 396.810 us; speedup vs baseline: 3.0190x; 1.3608x over previous
//
#include <hip/hip_runtime.h>
#include <math.h>

#define NNODES 100000
#define NEDGES 1600000
#define CH 64
#define CH2 128
#define NLAYERS 3
#define NBLK 98            // ceil(100000 / 1024) scan blocks
#define NPB 512            // nodes per bucket (d >> 9)
#define NBKT 196           // ceil(100000 / 512)
#define BKT_CAP 10240      // slots per bucket region (mean 8192 + 22 sigma)
#define CHUNK 8192         // edges per bfill2 block
#define KPT 32             // edges per thread in bfill2

typedef unsigned int uint;
typedef unsigned short ushort;

// round-to-nearest-even f32 -> bf16 (finite inputs)
__device__ __forceinline__ ushort f2bf(float f) {
    uint u = __float_as_uint(f);
    u = (u + 0x7fffu + ((u >> 16) & 1u)) >> 16;
    return (ushort)u;
}
__device__ __forceinline__ float bflo(uint p) { return __uint_as_float(p << 16); }
__device__ __forceinline__ float bfhi(uint p) { return __uint_as_float(p & 0xffff0000u); }

// ---------------- bucketed CSR build ----------------

__global__ void binit_kernel(int* __restrict__ bcur) {
    int b = blockIdx.x * 256 + threadIdx.x;
    if (b < NBKT) bcur[b] = b * BKT_CAP;
}

// Level 1: block-coalesced bucket scatter. Per block: LDS histogram over 196
// buckets -> ONE global atomic per (block,bucket) claims a contiguous run ->
// LDS-rank placement. Writes are ~consecutive runs, not per-edge random stores.
__global__ __launch_bounds__(256) void bfill2_kernel(const int* __restrict__ src,
                                                     const int* __restrict__ dst,
                                                     int* __restrict__ bcur,
                                                     int2* __restrict__ epair) {
    __shared__ int hcnt[NBKT];
    __shared__ int hbase[NBKT];
    int t = threadIdx.x;
    int e0 = blockIdx.x * CHUNK;

    for (int b = t; b < NBKT; b += 256) hcnt[b] = 0;
    __syncthreads();

#pragma unroll
    for (int i = 0; i < KPT; ++i) {
        int e = e0 + i * 256 + t;                 // coalesced
        if (e < NEDGES) atomicAdd(&hcnt[dst[e] >> 9], 1);
    }
    __syncthreads();

    for (int b = t; b < NBKT; b += 256) {
        int c = hcnt[b];
        hbase[b] = c ? atomicAdd(&bcur[b], c) : 0;
        hcnt[b] = 0;                              // reuse as local cursor
    }
    __syncthreads();

#pragma unroll
    for (int i = 0; i < KPT; ++i) {
        int e = e0 + i * 256 + t;
        if (e < NEDGES) {
            int s = src[e];
            int d = dst[e];
            int bkt = d >> 9;
            int r = atomicAdd(&hcnt[bkt], 1);
            epair[hbase[bkt] + r] = make_int2(s, d);
        }
    }
}

// per-bucket node-degree count from the bucket's contiguous segment (replaces
// the global-atomic hist AND the cnt memset: every node is written exactly once)
__global__ __launch_bounds__(256) void bcount_kernel(const int* __restrict__ bcur,
                                                     const int2* __restrict__ epair,
                                                     int* __restrict__ cnt) {
    __shared__ int lcnt[NPB];
    int b = blockIdx.x;
    int n0 = b * NPB;
    int n1 = n0 + NPB; if (n1 > NNODES) n1 = NNODES;
    int t = threadIdx.x;
    for (int i = t; i < NPB; i += 256) lcnt[i] = 0;
    __syncthreads();
    int seg0 = b * BKT_CAP;
    int seg1 = bcur[b];
    for (int i = seg0 + t; i < seg1; i += 256) {
        int d = epair[i].y;
        atomicAdd(&lcnt[d - n0], 1);
    }
    __syncthreads();
    for (int i = t; i < n1 - n0; i += 256) cnt[n0 + i] = lcnt[i];
}

__global__ void dinv_kernel(const int* __restrict__ cnt, float* __restrict__ dinv, int n) {
    int t = blockIdx.x * blockDim.x + threadIdx.x;
    if (t < n) dinv[t] = rsqrtf((float)cnt[t] + 1.0f);   // +1 self-loop
}

// ---- 3-pass parallel exclusive scan over cnt[100000] -> rowptr ----

__global__ __launch_bounds__(256) void bsum_kernel(const int* __restrict__ cnt,
                                                   int* __restrict__ bsum) {
    int t = threadIdx.x;
    int base = blockIdx.x * 1024 + t * 4;
    int s = 0;
#pragma unroll
    for (int i = 0; i < 4; ++i) { int k = base + i; if (k < NNODES) s += cnt[k]; }
    __shared__ int ls[256];
    ls[t] = s; __syncthreads();
    for (int off = 128; off > 0; off >>= 1) {
        if (t < off) ls[t] += ls[t + off];
        __syncthreads();
    }
    if (t == 0) bsum[blockIdx.x] = ls[0];
}

__global__ __launch_bounds__(128) void bscan_kernel(const int* __restrict__ bsum,
                                                    int* __restrict__ boff,
                                                    int* __restrict__ rowptr) {
    __shared__ int s[128];
    int t = threadIdx.x;
    int v = (t < NBLK) ? bsum[t] : 0;
    s[t] = v; __syncthreads();
    for (int off = 1; off < 128; off <<= 1) {
        int u = (t >= off) ? s[t - off] : 0;
        __syncthreads();
        s[t] += u;
        __syncthreads();
    }
    if (t < NBLK) boff[t] = s[t] - v;   // exclusive
    if (t == 0) rowptr[NNODES] = NEDGES;
}

__global__ __launch_bounds__(256) void scanb_kernel(const int* __restrict__ cnt,
                                                    const int* __restrict__ boff,
                                                    int* __restrict__ rowptr) {
    int t = threadIdx.x;
    int base = blockIdx.x * 1024 + t * 4;
    int v[4]; int tsum = 0;
#pragma unroll
    for (int i = 0; i < 4; ++i) { int k = base + i; v[i] = (k < NNODES) ? cnt[k] : 0; tsum += v[i]; }
    __shared__ int ls[256];
    ls[t] = tsum; __syncthreads();
    for (int off = 1; off < 256; off <<= 1) {
        int u = (t >= off) ? ls[t - off] : 0;
        __syncthreads();
        ls[t] += u;
        __syncthreads();
    }
    int run = boff[blockIdx.x] + ls[t] - tsum;
#pragma unroll
    for (int i = 0; i < 4; ++i) {
        int k = base + i;
        if (k < NNODES) { rowptr[k] = run; run += v[i]; }
    }
}

// Level 2: one block per bucket; place srcs at exact rowptr positions via LDS
// cursors. Writes stay inside the bucket's own CSR segment (~32KB, L2-local).
__global__ __launch_bounds__(256) void bsort_kernel(const int* __restrict__ rowptr,
                                                    const int* __restrict__ bcur,
                                                    const int2* __restrict__ epair,
                                                    int* __restrict__ esrc) {
    __shared__ int cur[NPB];
    int b = blockIdx.x;
    int n0 = b * NPB;
    if (n0 >= NNODES) return;
    int n1 = n0 + NPB; if (n1 > NNODES) n1 = NNODES;
    int t = threadIdx.x;
    for (int i = t; i < n1 - n0; i += 256) cur[i] = rowptr[n0 + i];
    __syncthreads();
    int seg0 = b * BKT_CAP;
    int seg1 = bcur[b];
    for (int i = seg0 + t; i < seg1; i += 256) {
        int2 p = epair[i];
        int pos = atomicAdd(&cur[p.y - n0], 1);
        esrc[pos] = p.x;
    }
}

// ---------------- y = bf16(dinv * x) (row-major), once for layer 0 ----------------

__global__ __launch_bounds__(256) void y0_kernel(const float* __restrict__ x,
                                                 const float* __restrict__ dinv,
                                                 ushort* __restrict__ y) {
    int t = blockIdx.x * 256 + threadIdx.x;
    if (t >= NNODES * CH) return;
    int node = t >> 6;
    y[t] = f2bf(dinv[node] * x[t]);
}

// ---------------- aggregation: z[d] = dinv[d]*(sum_{s in N(d)} y[s] + y[d]) ----------------
// bf16 y, 8 edges in flight per iteration: group g (8 lanes) loads edge j+g's 128B row
// as uint4 (16B = 8 bf16)/lane. f32 accumulation. All shuffles wave-uniform.

__global__ __launch_bounds__(256) void agg8_kernel(const int* __restrict__ rowptr,
                                                   const int* __restrict__ esrc,
                                                   const ushort* __restrict__ y,
                                                   const float* __restrict__ dinv,
                                                   float* __restrict__ z) {
    int w = (blockIdx.x * 256 + threadIdx.x) >> 6;   // node id
    int lane = threadIdx.x & 63;
    if (w >= NNODES) return;
    int g = lane >> 3;        // edge subgroup 0..7
    int q = lane & 7;         // slot: 8 bf16 channels at q*8

    int start = rowptr[w];
    int end   = rowptr[w + 1];
    float acc[8];
#pragma unroll
    for (int i = 0; i < 8; ++i) acc[i] = 0.0f;

    for (int base = start; base < end; base += 64) {
        int m = end - base; if (m > 64) m = 64;       // wave-uniform
        int e = (lane < m) ? esrc[base + lane] : 0;   // coalesced 4B/lane
        int m8 = m & ~7;
        int j = 0;
#pragma unroll 2
        for (; j < m8; j += 8) {                      // wave-uniform trip count
            int s = __shfl(e, j + g, 64);
            uint4 v = *(const uint4*)(y + (size_t)s * CH + q * 8);
            acc[0] += bflo(v.x); acc[1] += bfhi(v.x);
            acc[2] += bflo(v.y); acc[3] += bfhi(v.y);
            acc[4] += bflo(v.z); acc[5] += bfhi(v.z);
            acc[6] += bflo(v.w); acc[7] += bfhi(v.w);
        }
        if (m8 < m) {                                 // wave-uniform condition
            int s = __shfl(e, m8 + g, 64);            // all lanes execute the shuffle
            if (m8 + g < m) {                         // only load+add predicated
                uint4 v = *(const uint4*)(y + (size_t)s * CH + q * 8);
                acc[0] += bflo(v.x); acc[1] += bfhi(v.x);
                acc[2] += bflo(v.y); acc[3] += bfhi(v.y);
                acc[4] += bflo(v.z); acc[5] += bfhi(v.z);
                acc[6] += bflo(v.w); acc[7] += bfhi(v.w);
            }
        }
    }

    // combine the 8 group partials (lanes equal mod 8) — wave-uniform
#pragma unroll
    for (int off = 8; off < 64; off <<= 1) {
#pragma unroll
        for (int i = 0; i < 8; ++i)
            acc[i] += __shfl_xor(acc[i], off, 64);
    }

    if (lane < 8) {
        uint4 sv = *(const uint4*)(y + (size_t)w * CH + lane * 8);   // self-loop
        float dv = dinv[w];
        float4 o0, o1;
        o0.x = dv * (acc[0] + bflo(sv.x));
        o0.y = dv * (acc[1] + bfhi(sv.x));
        o0.z = dv * (acc[2] + bflo(sv.y));
        o0.w = dv * (acc[3] + bfhi(sv.y));
        o1.x = dv * (acc[4] + bflo(sv.z));
        o1.y = dv * (acc[5] + bfhi(sv.z));
        o1.z = dv * (acc[6] + bflo(sv.w));
        o1.w = dv * (acc[7] + bfhi(sv.w));
        *(float4*)(z + (size_t)w * CH + lane * 8)     = o0;
        *(float4*)(z + (size_t)w * CH + lane * 8 + 4) = o1;
    }
}

// ---------------- fused GEMM + bias + GLU + residual (+ bf16 y for next layer) ----------------

__global__ __launch_bounds__(256) void gemm_glu_kernel(const float* __restrict__ z,
                                                       const float* __restrict__ W,
                                                       const float* __restrict__ b,
                                                       const float* __restrict__ xold,
                                                       const float* __restrict__ dinv,
                                                       float* __restrict__ xnew,
                                                       ushort* __restrict__ ynext,
                                                       int write_y) {
    __shared__ float Wl[CH * CH2];   // 32 KB
    __shared__ float Zl[16 * CH];    // 4 KB
    int t = threadIdx.x;

    const float4* W4 = (const float4*)W;
    float4* Wl4 = (float4*)Wl;
#pragma unroll
    for (int i = 0; i < 8; ++i) Wl4[t + 256 * i] = W4[t + 256 * i];

    int row0 = blockIdx.x * 16;
    ((float4*)Zl)[t] = ((const float4*)(z + (size_t)row0 * CH))[t];
    __syncthreads();

    int c  = t & 63;          // channel
    int rg = t >> 6;          // 0..3 -> rows rg*4 .. rg*4+3 (wave-uniform)
    float accA[4] = {0.f, 0.f, 0.f, 0.f};
    float accG[4] = {0.f, 0.f, 0.f, 0.f};

#pragma unroll 4
    for (int k = 0; k < CH; ++k) {
        float wa = Wl[k * CH2 + c];
        float wg = Wl[k * CH2 + 64 + c];
#pragma unroll
        for (int i = 0; i < 4; ++i) {
            float zv = Zl[(rg * 4 + i) * CH + k];   // wave-uniform broadcast
            accA[i] += zv * wa;
            accG[i] += zv * wg;
        }
    }

    float ba = b[c], bg = b[64 + c];
#pragma unroll
    for (int i = 0; i < 4; ++i) {
        int row = row0 + rg * 4 + i;
        size_t idx = (size_t)row * CH + c;
        float a = accA[i] + ba;
        float gv = accG[i] + bg;
        float sg = 1.0f / (1.0f + expf(-gv));
        float xv = a * sg + xold[idx];
        xnew[idx] = xv;
        if (write_y)
            ynext[idx] = f2bf(dinv[row] * xv);
    }
}

// ---------------- launch ----------------

extern "C" void kernel_launch(void* const* d_in, const int* in_sizes, int n_in,
                              void* d_out, int out_size, void* d_ws, size_t ws_size,
                              hipStream_t stream) {
    const float* x_in = (const float*)d_in[0];              // [N,64]
    const float* Ws   = (const float*)d_in[1];              // [3,64,128]
    const float* bs   = (const float*)d_in[2];              // [3,128]
    const int*   ei   = (const int*)d_in[3];                // [2,E]
    const int* src = ei;
    const int* dst = ei + NEDGES;

    char* wsb = (char*)d_ws;
    int*    cnt    = (int*)wsb;                               // 400KB
    float*  dinv   = (float*)(wsb + 512 * 1024);              // 400KB
    int*    rowptr = (int*)(wsb + 1024 * 1024);               // 400KB+4
    int*    bsum   = (int*)(wsb + 1536 * 1024);               // 98 ints
    int*    boff   = bsum + 128;
    int*    bcur   = (int*)(wsb + 1792 * 1024);               // 196 ints
    int*    esrc   = (int*)(wsb + 2 * 1024 * 1024);           // E ints = 6.4 MB
    int2*   epair  = (int2*)(wsb + 9 * 1024 * 1024);          // 196*10240 int2 = 16.06 MB
    ushort* y      = (ushort*)(wsb + 26 * 1024 * 1024);       // N*64 bf16 = 12.8 MB
    float*  z      = (float*)(wsb + 39 * 1024 * 1024);        // N*64 f32 = 25.6 MB
    float*  xbuf   = (float*)(wsb + 65 * 1024 * 1024);        // N*64 f32 = 25.6 MB

    // ---- CSR build (once; reused by all layers) ----
    binit_kernel<<<1, 256, 0, stream>>>(bcur);
    bfill2_kernel<<<(NEDGES + CHUNK - 1) / CHUNK, 256, 0, stream>>>(src, dst, bcur, epair);
    bcount_kernel<<<NBKT, 256, 0, stream>>>(bcur, epair, cnt);
    dinv_kernel<<<(NNODES + 255) / 256, 256, 0, stream>>>(cnt, dinv, NNODES);
    bsum_kernel<<<NBLK, 256, 0, stream>>>(cnt, bsum);
    bscan_kernel<<<1, 128, 0, stream>>>(bsum, boff, rowptr);
    scanb_kernel<<<NBLK, 256, 0, stream>>>(cnt, boff, rowptr);
    bsort_kernel<<<NBKT, 256, 0, stream>>>(rowptr, bcur, epair, esrc);
    y0_kernel<<<(NNODES * CH + 255) / 256, 256, 0, stream>>>(x_in, dinv, y);

    const float* xl = x_in;
    for (int l = 0; l < NLAYERS; ++l) {
        const float* W = Ws + (size_t)l * CH * CH2;
        const float* b = bs + (size_t)l * CH2;
        float* xout = (l == NLAYERS - 1) ? (float*)d_out : xbuf;

        agg8_kernel<<<(NNODES * 64 + 255) / 256, 256, 0, stream>>>(rowptr, esrc, y, dinv, z);
        gemm_glu_kernel<<<NNODES / 16, 256, 0, stream>>>(z, W, b, xl, dinv, xout, y,
                                                         (l < NLAYERS - 1) ? 1 : 0);

        xl = xout;   // middle layer in-place on xbuf: each element read+written by one thread
    }
}

// Round 12
// 329.906 us; speedup vs baseline: 3.6312x; 1.2028x over previous
//
#include <hip/hip_runtime.h>
#include <math.h>

#define NNODES 100000
#define NEDGES 1600000
#define CH 64
#define CH2 128
#define NLAYERS 3
#define NBLK 98            // ceil(100000 / 1024) scan blocks
#define NPB 512            // nodes per bucket (d >> 9)
#define NBKT 196           // ceil(100000 / 512)
#define BKT_CAP 10240      // slots per bucket region (mean 8192 + 22 sigma)
#define CHUNK 8192         // edges per bfill2 block
#define KPT 32             // edges per thread in bfill2

typedef unsigned int uint;
typedef unsigned short ushort;
typedef __attribute__((ext_vector_type(8))) short bf16x8;
typedef __attribute__((ext_vector_type(4))) float f32x4;

// round-to-nearest-even f32 -> bf16 (finite inputs)
__device__ __forceinline__ ushort f2bf(float f) {
    uint u = __float_as_uint(f);
    u = (u + 0x7fffu + ((u >> 16) & 1u)) >> 16;
    return (ushort)u;
}
__device__ __forceinline__ float bflo(uint p) { return __uint_as_float(p << 16); }
__device__ __forceinline__ float bfhi(uint p) { return __uint_as_float(p & 0xffff0000u); }

union U8 { uint4 u; bf16x8 v; ushort s[8]; };
__device__ __forceinline__ bf16x8 ld8(const ushort* p) {
    U8 t; t.u = *(const uint4*)p; return t.v;
}

// ---------------- bucketed CSR build ----------------

__global__ void binit_kernel(int* __restrict__ bcur) {
    int b = blockIdx.x * 256 + threadIdx.x;
    if (b < NBKT) bcur[b] = b * BKT_CAP;
}

// Level 1: block-coalesced bucket scatter. One global atomic per (block,bucket)
// claims a contiguous run; LDS-rank placement -> near-sequential writes.
__global__ __launch_bounds__(256) void bfill2_kernel(const int* __restrict__ src,
                                                     const int* __restrict__ dst,
                                                     int* __restrict__ bcur,
                                                     int2* __restrict__ epair) {
    __shared__ int hcnt[NBKT];
    __shared__ int hbase[NBKT];
    int t = threadIdx.x;
    int e0 = blockIdx.x * CHUNK;

    for (int b = t; b < NBKT; b += 256) hcnt[b] = 0;
    __syncthreads();

#pragma unroll
    for (int i = 0; i < KPT; ++i) {
        int e = e0 + i * 256 + t;                 // coalesced
        if (e < NEDGES) atomicAdd(&hcnt[dst[e] >> 9], 1);
    }
    __syncthreads();

    for (int b = t; b < NBKT; b += 256) {
        int c = hcnt[b];
        hbase[b] = c ? atomicAdd(&bcur[b], c) : 0;
        hcnt[b] = 0;                              // reuse as local cursor
    }
    __syncthreads();

#pragma unroll
    for (int i = 0; i < KPT; ++i) {
        int e = e0 + i * 256 + t;
        if (e < NEDGES) {
            int s = src[e];
            int d = dst[e];
            int bkt = d >> 9;
            int r = atomicAdd(&hcnt[bkt], 1);
            epair[hbase[bkt] + r] = make_int2(s, d);
        }
    }
}

// per-bucket node-degree count from the bucket's contiguous segment
__global__ __launch_bounds__(256) void bcount_kernel(const int* __restrict__ bcur,
                                                     const int2* __restrict__ epair,
                                                     int* __restrict__ cnt) {
    __shared__ int lcnt[NPB];
    int b = blockIdx.x;
    int n0 = b * NPB;
    int n1 = n0 + NPB; if (n1 > NNODES) n1 = NNODES;
    int t = threadIdx.x;
    for (int i = t; i < NPB; i += 256) lcnt[i] = 0;
    __syncthreads();
    int seg0 = b * BKT_CAP;
    int seg1 = bcur[b];
    for (int i = seg0 + t; i < seg1; i += 256) {
        int d = epair[i].y;
        atomicAdd(&lcnt[d - n0], 1);
    }
    __syncthreads();
    for (int i = t; i < n1 - n0; i += 256) cnt[n0 + i] = lcnt[i];
}

__global__ void dinv_kernel(const int* __restrict__ cnt, float* __restrict__ dinv, int n) {
    int t = blockIdx.x * blockDim.x + threadIdx.x;
    if (t < n) dinv[t] = rsqrtf((float)cnt[t] + 1.0f);   // +1 self-loop
}

// ---- 3-pass parallel exclusive scan over cnt[100000] -> rowptr ----

__global__ __launch_bounds__(256) void bsum_kernel(const int* __restrict__ cnt,
                                                   int* __restrict__ bsum) {
    int t = threadIdx.x;
    int base = blockIdx.x * 1024 + t * 4;
    int s = 0;
#pragma unroll
    for (int i = 0; i < 4; ++i) { int k = base + i; if (k < NNODES) s += cnt[k]; }
    __shared__ int ls[256];
    ls[t] = s; __syncthreads();
    for (int off = 128; off > 0; off >>= 1) {
        if (t < off) ls[t] += ls[t + off];
        __syncthreads();
    }
    if (t == 0) bsum[blockIdx.x] = ls[0];
}

__global__ __launch_bounds__(128) void bscan_kernel(const int* __restrict__ bsum,
                                                    int* __restrict__ boff,
                                                    int* __restrict__ rowptr) {
    __shared__ int s[128];
    int t = threadIdx.x;
    int v = (t < NBLK) ? bsum[t] : 0;
    s[t] = v; __syncthreads();
    for (int off = 1; off < 128; off <<= 1) {
        int u = (t >= off) ? s[t - off] : 0;
        __syncthreads();
        s[t] += u;
        __syncthreads();
    }
    if (t < NBLK) boff[t] = s[t] - v;   // exclusive
    if (t == 0) rowptr[NNODES] = NEDGES;
}

__global__ __launch_bounds__(256) void scanb_kernel(const int* __restrict__ cnt,
                                                    const int* __restrict__ boff,
                                                    int* __restrict__ rowptr) {
    int t = threadIdx.x;
    int base = blockIdx.x * 1024 + t * 4;
    int v[4]; int tsum = 0;
#pragma unroll
    for (int i = 0; i < 4; ++i) { int k = base + i; v[i] = (k < NNODES) ? cnt[k] : 0; tsum += v[i]; }
    __shared__ int ls[256];
    ls[t] = tsum; __syncthreads();
    for (int off = 1; off < 256; off <<= 1) {
        int u = (t >= off) ? ls[t - off] : 0;
        __syncthreads();
        ls[t] += u;
        __syncthreads();
    }
    int run = boff[blockIdx.x] + ls[t] - tsum;
#pragma unroll
    for (int i = 0; i < 4; ++i) {
        int k = base + i;
        if (k < NNODES) { rowptr[k] = run; run += v[i]; }
    }
}

// Level 2: one block per bucket; place srcs at exact rowptr positions via LDS cursors.
__global__ __launch_bounds__(256) void bsort_kernel(const int* __restrict__ rowptr,
                                                    const int* __restrict__ bcur,
                                                    const int2* __restrict__ epair,
                                                    int* __restrict__ esrc) {
    __shared__ int cur[NPB];
    int b = blockIdx.x;
    int n0 = b * NPB;
    if (n0 >= NNODES) return;
    int n1 = n0 + NPB; if (n1 > NNODES) n1 = NNODES;
    int t = threadIdx.x;
    for (int i = t; i < n1 - n0; i += 256) cur[i] = rowptr[n0 + i];
    __syncthreads();
    int seg0 = b * BKT_CAP;
    int seg1 = bcur[b];
    for (int i = seg0 + t; i < seg1; i += 256) {
        int2 p = epair[i];
        int pos = atomicAdd(&cur[p.y - n0], 1);
        esrc[pos] = p.x;
    }
}

// ---------------- y = bf16(dinv * x) (row-major), once for layer 0 ----------------

__global__ __launch_bounds__(256) void y0_kernel(const float* __restrict__ x,
                                                 const float* __restrict__ dinv,
                                                 ushort* __restrict__ y) {
    int t = blockIdx.x * 256 + threadIdx.x;
    if (t >= NNODES * CH) return;
    int node = t >> 6;
    y[t] = f2bf(dinv[node] * x[t]);
}

// ---------------- W -> bf16 MFMA B-fragment order ----------------
// Wfrag[l][n(0..7)][kh(0..1)][lane(0..63)][j(0..7)] = bf16(W[l][kh*32+(lane>>4)*8+j][n*16+(lane&15)])

__global__ void wconv_kernel(const float* __restrict__ Ws, ushort* __restrict__ Wfrag) {
    int t = blockIdx.x * 256 + threadIdx.x;
    if (t >= NLAYERS * 8 * 2 * 64) return;
    int lane = t & 63;
    int kh = (t >> 6) & 1;
    int n = (t >> 7) & 7;
    int l = t >> 10;
    ushort o[8];
#pragma unroll
    for (int j = 0; j < 8; ++j) {
        int k = kh * 32 + (lane >> 4) * 8 + j;
        int col = n * 16 + (lane & 15);
        o[j] = f2bf(Ws[(size_t)l * CH * CH2 + (size_t)k * CH2 + col]);
    }
    *(uint4*)(Wfrag + (size_t)t * 8) = *(uint4*)o;
}

// ---------------- aggregation: z[d] = bf16(dinv[d]*(sum y[s] + y[d])) ----------------
// bf16 y, 8 edges in flight; f32 accumulation; z written bf16 (feeds MFMA GEMM).

__global__ __launch_bounds__(256) void agg8_kernel(const int* __restrict__ rowptr,
                                                   const int* __restrict__ esrc,
                                                   const ushort* __restrict__ y,
                                                   const float* __restrict__ dinv,
                                                   ushort* __restrict__ z) {
    int w = (blockIdx.x * 256 + threadIdx.x) >> 6;   // node id
    int lane = threadIdx.x & 63;
    if (w >= NNODES) return;
    int g = lane >> 3;        // edge subgroup 0..7
    int q = lane & 7;         // slot: 8 bf16 channels at q*8

    int start = rowptr[w];
    int end   = rowptr[w + 1];
    float acc[8];
#pragma unroll
    for (int i = 0; i < 8; ++i) acc[i] = 0.0f;

    for (int base = start; base < end; base += 64) {
        int m = end - base; if (m > 64) m = 64;       // wave-uniform
        int e = (lane < m) ? esrc[base + lane] : 0;   // coalesced 4B/lane
        int m8 = m & ~7;
        int j = 0;
#pragma unroll 2
        for (; j < m8; j += 8) {                      // wave-uniform trip count
            int s = __shfl(e, j + g, 64);
            uint4 v = *(const uint4*)(y + (size_t)s * CH + q * 8);
            acc[0] += bflo(v.x); acc[1] += bfhi(v.x);
            acc[2] += bflo(v.y); acc[3] += bfhi(v.y);
            acc[4] += bflo(v.z); acc[5] += bfhi(v.z);
            acc[6] += bflo(v.w); acc[7] += bfhi(v.w);
        }
        if (m8 < m) {                                 // wave-uniform condition
            int s = __shfl(e, m8 + g, 64);            // all lanes execute the shuffle
            if (m8 + g < m) {                         // only load+add predicated
                uint4 v = *(const uint4*)(y + (size_t)s * CH + q * 8);
                acc[0] += bflo(v.x); acc[1] += bfhi(v.x);
                acc[2] += bflo(v.y); acc[3] += bfhi(v.y);
                acc[4] += bflo(v.z); acc[5] += bfhi(v.z);
                acc[6] += bflo(v.w); acc[7] += bfhi(v.w);
            }
        }
    }

    // combine the 8 group partials (lanes equal mod 8) — wave-uniform
#pragma unroll
    for (int off = 8; off < 64; off <<= 1) {
#pragma unroll
        for (int i = 0; i < 8; ++i)
            acc[i] += __shfl_xor(acc[i], off, 64);
    }

    if (lane < 8) {
        uint4 sv = *(const uint4*)(y + (size_t)w * CH + lane * 8);   // self-loop
        float dv = dinv[w];
        U8 o;
        o.s[0] = f2bf(dv * (acc[0] + bflo(sv.x)));
        o.s[1] = f2bf(dv * (acc[1] + bfhi(sv.x)));
        o.s[2] = f2bf(dv * (acc[2] + bflo(sv.y)));
        o.s[3] = f2bf(dv * (acc[3] + bfhi(sv.y)));
        o.s[4] = f2bf(dv * (acc[4] + bflo(sv.z)));
        o.s[5] = f2bf(dv * (acc[5] + bfhi(sv.z)));
        o.s[6] = f2bf(dv * (acc[6] + bflo(sv.w)));
        o.s[7] = f2bf(dv * (acc[7] + bfhi(sv.w)));
        *(uint4*)(z + (size_t)w * CH + lane * 8) = o.u;
    }
}

// ---------------- MFMA GEMM + bias + GLU + residual (+ bf16 y for next layer) ----------------
// One wave per 16 rows; 8 col-tiles x 2 K-MFMAs of v_mfma_f32_16x16x32_bf16.
// A: row=lane&15, k=(lane>>4)*8+j (contiguous in z). B: pre-packed Wfrag. No LDS.
// D: col=lane&15, row=(lane>>4)*4+reg (m89-verified layout).

__global__ __launch_bounds__(256) void gemm_glu_mfma_kernel(const ushort* __restrict__ z,
                                                            const ushort* __restrict__ Wfrag,
                                                            const float* __restrict__ b,
                                                            const float* __restrict__ xold,
                                                            const float* __restrict__ dinv,
                                                            float* __restrict__ xnew,
                                                            ushort* __restrict__ ynext,
                                                            int write_y) {
    int wid  = threadIdx.x >> 6;
    int lane = threadIdx.x & 63;
    int row0 = blockIdx.x * 64 + wid * 16;
    if (row0 >= NNODES) return;            // wave-uniform (N % 16 == 0)
    int rl = lane & 15;
    int h  = lane >> 4;                    // 0..3

    const ushort* zp = z + (size_t)(row0 + rl) * CH + h * 8;
    bf16x8 a0 = ld8(zp);                   // k = 0..31 across h
    bf16x8 a1 = ld8(zp + 32);              // k = 32..63

    f32x4 acc[8];
#pragma unroll
    for (int n = 0; n < 8; ++n) {
        bf16x8 b0 = ld8(Wfrag + ((size_t)(n * 2 + 0) * 64 + lane) * 8);
        bf16x8 b1 = ld8(Wfrag + ((size_t)(n * 2 + 1) * 64 + lane) * 8);
        f32x4 c = {0.f, 0.f, 0.f, 0.f};
        c = __builtin_amdgcn_mfma_f32_16x16x32_bf16(a0, b0, c, 0, 0, 0);
        c = __builtin_amdgcn_mfma_f32_16x16x32_bf16(a1, b1, c, 0, 0, 0);
        acc[n] = c;
    }

    float ba[4], bg[4];
#pragma unroll
    for (int n = 0; n < 4; ++n) { ba[n] = b[n * 16 + rl]; bg[n] = b[64 + n * 16 + rl]; }

#pragma unroll
    for (int reg = 0; reg < 4; ++reg) {
        int row = row0 + h * 4 + reg;
        float dv = dinv[row];
#pragma unroll
        for (int n = 0; n < 4; ++n) {
            int c = n * 16 + rl;
            size_t idx = (size_t)row * CH + c;
            float a  = acc[n][reg] + ba[n];
            float gv = acc[n + 4][reg] + bg[n];
            float sg = 1.0f / (1.0f + expf(-gv));
            float xv = a * sg + xold[idx];
            xnew[idx] = xv;
            if (write_y) ynext[idx] = f2bf(dv * xv);
        }
    }
}

// ---------------- launch ----------------

extern "C" void kernel_launch(void* const* d_in, const int* in_sizes, int n_in,
                              void* d_out, int out_size, void* d_ws, size_t ws_size,
                              hipStream_t stream) {
    const float* x_in = (const float*)d_in[0];              // [N,64]
    const float* Ws   = (const float*)d_in[1];              // [3,64,128]
    const float* bs   = (const float*)d_in[2];              // [3,128]
    const int*   ei   = (const int*)d_in[3];                // [2,E]
    const int* src = ei;
    const int* dst = ei + NEDGES;

    char* wsb = (char*)d_ws;
    int*    cnt    = (int*)wsb;                               // 400KB
    float*  dinv   = (float*)(wsb + 512 * 1024);              // 400KB
    int*    rowptr = (int*)(wsb + 1024 * 1024);               // 400KB+4
    int*    bsum   = (int*)(wsb + 1536 * 1024);               // 98 ints
    int*    boff   = bsum + 128;
    int*    bcur   = (int*)(wsb + 1792 * 1024);               // 196 ints
    ushort* Wfrag  = (ushort*)(wsb + 1856 * 1024);            // 3*1024*8 ushort = 48KB
    int*    esrc   = (int*)(wsb + 2 * 1024 * 1024);           // E ints = 6.4 MB
    int2*   epair  = (int2*)(wsb + 9 * 1024 * 1024);          // 196*10240 int2 = 16.06 MB
    ushort* y      = (ushort*)(wsb + 26 * 1024 * 1024);       // N*64 bf16 = 12.8 MB
    ushort* z      = (ushort*)(wsb + 39 * 1024 * 1024);       // N*64 bf16 = 12.8 MB
    float*  xbuf   = (float*)(wsb + 52 * 1024 * 1024);        // N*64 f32 = 25.6 MB

    // ---- CSR build + W pack (once; reused by all layers) ----
    binit_kernel<<<1, 256, 0, stream>>>(bcur);
    bfill2_kernel<<<(NEDGES + CHUNK - 1) / CHUNK, 256, 0, stream>>>(src, dst, bcur, epair);
    bcount_kernel<<<NBKT, 256, 0, stream>>>(bcur, epair, cnt);
    dinv_kernel<<<(NNODES + 255) / 256, 256, 0, stream>>>(cnt, dinv, NNODES);
    bsum_kernel<<<NBLK, 256, 0, stream>>>(cnt, bsum);
    bscan_kernel<<<1, 128, 0, stream>>>(bsum, boff, rowptr);
    scanb_kernel<<<NBLK, 256, 0, stream>>>(cnt, boff, rowptr);
    bsort_kernel<<<NBKT, 256, 0, stream>>>(rowptr, bcur, epair, esrc);
    wconv_kernel<<<(NLAYERS * 1024 + 255) / 256, 256, 0, stream>>>(Ws, Wfrag);
    y0_kernel<<<(NNODES * CH + 255) / 256, 256, 0, stream>>>(x_in, dinv, y);

    const float* xl = x_in;
    for (int l = 0; l < NLAYERS; ++l) {
        const ushort* Wf = Wfrag + (size_t)l * 1024 * 8;
        const float*  b  = bs + (size_t)l * CH2;
        float* xout = (l == NLAYERS - 1) ? (float*)d_out : xbuf;

        agg8_kernel<<<(NNODES * 64 + 255) / 256, 256, 0, stream>>>(rowptr, esrc, y, dinv, z);
        gemm_glu_mfma_kernel<<<(NNODES + 63) / 64, 256, 0, stream>>>(z, Wf, b, xl, dinv, xout, y,
                                                                     (l < NLAYERS - 1) ? 1 : 0);

        xl = xout;   // middle layer in-place on xbuf: each element read+written by one thread
    }
}